// Round 1
// baseline (149.951 us; speedup 1.0000x reference)
//
#include <hip/hip_runtime.h>
#include <hip/hip_bf16.h>
#include <stdint.h>

// out[e,o] = relu( sum_d (emb[src[e],d] + emb[dst[e],d]) * W[o,d] + b[o] )
// E = 600000, D_IN = D_OUT = 128.

using bf16x8 = __attribute__((ext_vector_type(8))) __bf16;
using f32x4  = __attribute__((ext_vector_type(4))) float;
using u16x8  = __attribute__((ext_vector_type(8))) unsigned short;
using u16x4  = __attribute__((ext_vector_type(4))) unsigned short;

static __device__ __forceinline__ unsigned short f2b(float f) {
    return __builtin_bit_cast(unsigned short, (__bf16)f);   // RNE fp32->bf16
}
static __device__ __forceinline__ float b2f(unsigned short u) {
    return __builtin_bit_cast(float, (unsigned int)u << 16); // exact bf16->fp32
}

// ---- prep: fp32 -> bf16 for node table and W (into d_ws) ----
__global__ void prep_cvt(const float* __restrict__ nodes,
                         const float* __restrict__ W,
                         unsigned short* __restrict__ nodes_b,
                         unsigned short* __restrict__ W_b,
                         int n_node4, int n_w4) {
    int i = blockIdx.x * blockDim.x + threadIdx.x;
    int stride = gridDim.x * blockDim.x;
    int total = n_node4 + n_w4;
    for (; i < total; i += stride) {
        const float4* src; unsigned short* dst; int j;
        if (i < n_node4) { src = (const float4*)nodes; dst = nodes_b; j = i; }
        else             { src = (const float4*)W;     dst = W_b;     j = i - n_node4; }
        float4 v = src[j];
        u16x4 r;
        r[0] = f2b(v.x); r[1] = f2b(v.y); r[2] = f2b(v.z); r[3] = f2b(v.w);
        *(u16x4*)&dst[(size_t)j * 4] = r;
    }
}

// ---- main: gather+add -> bf16 LDS tile -> MFMA GEMM vs W^T -> bias+relu ----
// Block: 256 thr (4 waves), 64 edges. Wave w: edges [w*16, w*16+16), all 128 outs.
// LDS tiles XOR-swizzled (elem ^= (row&7)<<3) to kill the D=128 bank conflict.
template<int BSRC>
__global__ __launch_bounds__(256, 3) void edge_linear(
    const float* __restrict__ nodes_f,
    const unsigned short* __restrict__ nodes_b,
    const int* __restrict__ e_src,
    const int* __restrict__ e_dst,
    const float* __restrict__ Wf,
    const unsigned short* __restrict__ Wb,
    const float* __restrict__ bias,
    float* __restrict__ out,
    int E)
{
    __shared__ __align__(16) unsigned short At[64 * 128];   // 16 KiB
    __shared__ __align__(16) unsigned short Wt[128 * 128];  // 32 KiB
    const int tid = threadIdx.x;
    const int eb  = blockIdx.x * 64;

    // stage W (bf16, swizzled): B[k=d][n=o] = W[o][d] -> rows of W are contiguous-k
    #pragma unroll
    for (int j = 0; j < 8; ++j) {
        int idx = j * 256 + tid;      // 2048 chunks of 8 elems
        int o = idx >> 4;             // output channel (row)
        int c = idx & 15;             // 8-elem chunk within row
        int elem = o * 128 + c * 8;
        int sw = elem ^ ((o & 7) << 3);
        if (BSRC) {
            u16x8 v = *(const u16x8*)&Wb[elem];
            *(u16x8*)&Wt[sw] = v;
        } else {
            const float4* wp = (const float4*)&Wf[elem];
            float4 a = wp[0], b4 = wp[1];
            u16x8 r;
            r[0] = f2b(a.x);  r[1] = f2b(a.y);  r[2] = f2b(a.z);  r[3] = f2b(a.w);
            r[4] = f2b(b4.x); r[5] = f2b(b4.y); r[6] = f2b(b4.z); r[7] = f2b(b4.w);
            *(u16x8*)&Wt[sw] = r;
        }
    }

    // stage A = emb[src] + emb[dst] (bf16, swizzled)
    if (BSRC) {
        #pragma unroll
        for (int j = 0; j < 4; ++j) {
            int idx = j * 256 + tid;  // 64 edges * 16 chunks
            int e = idx >> 4;
            int c = idx & 15;
            int eg = eb + e; if (eg >= E) eg = E - 1;
            int s = e_src[eg], d = e_dst[eg];
            u16x8 sv = *(const u16x8*)&nodes_b[(size_t)s * 128 + c * 8];
            u16x8 dv = *(const u16x8*)&nodes_b[(size_t)d * 128 + c * 8];
            u16x8 r;
            #pragma unroll
            for (int q = 0; q < 8; ++q) r[q] = f2b(b2f(sv[q]) + b2f(dv[q]));
            *(u16x8*)&At[(e * 128 + c * 8) ^ ((e & 7) << 3)] = r;
        }
    } else {
        #pragma unroll
        for (int j = 0; j < 8; ++j) {
            int idx = j * 256 + tid;  // 64 edges * 32 float4 chunks
            int e = idx >> 5;
            int c = idx & 31;
            int eg = eb + e; if (eg >= E) eg = E - 1;
            int s = e_src[eg], d = e_dst[eg];
            float4 sv = *(const float4*)&nodes_f[(size_t)s * 128 + c * 4];
            float4 dv = *(const float4*)&nodes_f[(size_t)d * 128 + c * 4];
            u16x4 r;
            r[0] = f2b(sv.x + dv.x); r[1] = f2b(sv.y + dv.y);
            r[2] = f2b(sv.z + dv.z); r[3] = f2b(sv.w + dv.w);
            *(u16x4*)&At[(e * 128 + c * 4) ^ ((e & 7) << 3)] = r;
        }
    }
    __syncthreads();

    const int wave = tid >> 6;
    const int lane = tid & 63;
    const int lr = lane & 15;   // A row / B col within fragment
    const int lg = lane >> 4;   // k-group

    f32x4 acc[8];
    #pragma unroll
    for (int n = 0; n < 8; ++n) acc[n] = (f32x4){0.f, 0.f, 0.f, 0.f};

    const int am = wave * 16 + lr;
    #pragma unroll
    for (int ks = 0; ks < 4; ++ks) {
        const int ka = ks * 32 + lg * 8;
        bf16x8 af = *(const bf16x8*)&At[(am * 128 + ka) ^ ((am & 7) << 3)];
        #pragma unroll
        for (int n = 0; n < 8; ++n) {
            const int o = n * 16 + lr;
            bf16x8 bf = *(const bf16x8*)&Wt[(o * 128 + ka) ^ ((o & 7) << 3)];
            acc[n] = __builtin_amdgcn_mfma_f32_16x16x32_bf16(af, bf, acc[n], 0, 0, 0);
        }
    }

    // epilogue: bias + relu + store. C/D map: col = lane&15, row = 4*(lane>>4)+reg.
    const int er0 = eb + wave * 16 + lg * 4;
    #pragma unroll
    for (int n = 0; n < 8; ++n) {
        const float bv = bias[n * 16 + lr];
        #pragma unroll
        for (int j2 = 0; j2 < 4; ++j2) {
            const int e = er0 + j2;
            if (e < E) {
                float v = acc[n][j2] + bv;
                out[(size_t)e * 128 + n * 16 + lr] = v > 0.f ? v : 0.f;
            }
        }
    }
}

extern "C" void kernel_launch(void* const* d_in, const int* in_sizes, int n_in,
                              void* d_out, int out_size, void* d_ws, size_t ws_size,
                              hipStream_t stream) {
    const float* nodes = (const float*)d_in[0];
    const int*   ei    = (const int*)d_in[1];     // [2][E] int32: row0=src, row1=dst
    const float* W     = (const float*)d_in[2];   // [128][128] fp32, row-major [o][d]
    const float* bias  = (const float*)d_in[3];   // [128] fp32
    float* out = (float*)d_out;

    const int n_node = in_sizes[0];               // 50000*128
    const int E      = in_sizes[1] / 2;           // 600000
    const int n_w    = in_sizes[2];               // 128*128

    const size_t node_bytes = (size_t)n_node * 2;
    const size_t need = node_bytes + (size_t)n_w * 2;
    const int blocks = (E + 63) / 64;

    if (ws_size >= need) {
        unsigned short* nodes_b = (unsigned short*)d_ws;
        unsigned short* W_b = (unsigned short*)((char*)d_ws + node_bytes);
        int n4 = n_node / 4, w4 = n_w / 4;
        int pgrid = (n4 + w4 + 255) / 256;
        if (pgrid > 2048) pgrid = 2048;
        prep_cvt<<<pgrid, 256, 0, stream>>>(nodes, W, nodes_b, W_b, n4, w4);
        edge_linear<1><<<blocks, 256, 0, stream>>>(nodes, nodes_b, ei, ei + E,
                                                   W, W_b, bias, out, E);
    } else {
        edge_linear<0><<<blocks, 256, 0, stream>>>(nodes, nullptr, ei, ei + E,
                                                   W, nullptr, bias, out, E);
    }
}